// Round 7
// baseline (417.597 us; speedup 1.0000x reference)
//
#include <hip/hip_runtime.h>
#include <hip/hip_bf16.h>
#include <math.h>

#define B_ 16
#define NT 64
#define LN 256
#define LV 4
#define D_ 256
#define VOCAB_ 32000
#define M_ 128
#define LS 4

typedef unsigned short ushort_t;
typedef unsigned int uint_t;

__device__ __forceinline__ ushort_t f2bf(float f) {
  uint_t u = __float_as_uint(f);
  uint_t r = u + 0x7FFFu + ((u >> 16) & 1u);
  return (ushort_t)(r >> 16);
}
__device__ __forceinline__ float bflo(uint_t u) {
  return __uint_as_float(u << 16);
}
__device__ __forceinline__ float bfhi(uint_t u) {
  return __uint_as_float(u & 0xFFFF0000u);
}

// ---------------- K_prep: S gather | C0->bf16 (colgroup-major) | transposes -
#define NB_S (3 * B_ * M_)  // 6144
#define NB_CONV 2048
#define NB_TR 192   // 768x256 -> 24x8 tiles of 32x32 (per weight)
#define NB_TQK 256
#define NB_WVT 64   // 256x256 -> 8x8 tiles
__global__ __launch_bounds__(256) void k_prep(
    const int* __restrict__ story, const float* __restrict__ C,
    const float* __restrict__ W_ih, const float* __restrict__ W_hh,
    const float* __restrict__ Wq, const float* __restrict__ Wk,
    const float* __restrict__ Wv, float* __restrict__ S,
    ushort_t* __restrict__ C0h, float* __restrict__ W_ihT,
    float* __restrict__ W_hhT, float* __restrict__ TQK,
    float* __restrict__ WvT) {
  __shared__ float smem[32 * 33];
  int blk = blockIdx.x, tid = threadIdx.x;
  if (blk < NB_S) {
    int h = blk / (B_ * M_);
    int bm = blk % (B_ * M_);
    const int* st = story + (size_t)bm * LS;
    const float* Ch = C + (size_t)h * VOCAB_ * D_;
    float s = Ch[(size_t)st[0] * D_ + tid] + Ch[(size_t)st[1] * D_ + tid] +
              Ch[(size_t)st[2] * D_ + tid] + Ch[(size_t)st[3] * D_ + tid];
    S[(size_t)blk * D_ + tid] = s;
  } else if (blk < NB_S + NB_CONV) {
    // C0 -> bf16, column-group-major: slice g (32 cols) contiguous (2 MB)
    int n4 = VOCAB_ * D_ / 4;
    for (int i = (blk - NB_S) * 256 + tid; i < n4; i += NB_CONV * 256) {
      float4 f = ((const float4*)C)[i];
      int v = i >> 6;       // row
      int c4 = i & 63;      // which float4 within row
      int g = c4 >> 3;      // col group (32 cols = 8 float4s)
      int o = c4 & 7;       // float4 within group
      uint2 packed;
      packed.x = (uint_t)f2bf(f.x) | ((uint_t)f2bf(f.y) << 16);
      packed.y = (uint_t)f2bf(f.z) | ((uint_t)f2bf(f.w) << 16);
      ((uint2*)C0h)[(size_t)g * VOCAB_ * 8 + (size_t)v * 8 + o] = packed;
    }
  } else if (blk < NB_S + NB_CONV + 2 * NB_TR) {
    int t = blk - (NB_S + NB_CONV);
    const float* W = W_ih;
    float* WT = W_ihT;
    if (t >= NB_TR) { t -= NB_TR; W = W_hh; WT = W_hhT; }
    const int R = 768;
    int tr = t % (R / 32), tc = t / (R / 32);
    int tx = tid & 31, ty = tid >> 5;
#pragma unroll
    for (int k = 0; k < 4; ++k)
      smem[(ty + 8 * k) * 33 + tx] =
          W[(size_t)(tr * 32 + ty + 8 * k) * D_ + tc * 32 + tx];
    __syncthreads();
#pragma unroll
    for (int k = 0; k < 4; ++k)
      WT[(size_t)(tc * 32 + ty + 8 * k) * R + tr * 32 + tx] =
          smem[tx * 33 + ty + 8 * k];
  } else if (blk < NB_S + NB_CONV + 2 * NB_TR + NB_TQK) {
    // TQK[j,i] = sum_k Wq[k,j] * Wk[k,i]
    int j = blk - (NB_S + NB_CONV + 2 * NB_TR);
    smem[tid] = Wq[(size_t)tid * D_ + j];
    __syncthreads();
    float acc = 0.f;
#pragma unroll 8
    for (int k = 0; k < D_; ++k) acc += smem[k] * Wk[(size_t)k * D_ + tid];
    TQK[(size_t)j * D_ + tid] = acc;
  } else {
    // WvT[j,r] = Wv[r,j]
    int t = blk - (NB_S + NB_CONV + 2 * NB_TR + NB_TQK);
    int tr = t & 7, tc = t >> 3;
    int tx = tid & 31, ty = tid >> 5;
#pragma unroll
    for (int k = 0; k < 4; ++k)
      smem[(ty + 8 * k) * 33 + tx] =
          Wv[(size_t)(tr * 32 + ty + 8 * k) * D_ + tc * 32 + tx];
    __syncthreads();
#pragma unroll
    for (int k = 0; k < 4; ++k)
      WvT[(size_t)(tc * 32 + ty + 8 * k) * D_ + tr * 32 + tx] =
          smem[tx * 33 + ty + 8 * k];
  }
}

// ---------------- K_rootsx: XCD-sliced gather + gates + tvec ----------------
// blk 0..6: gates/tvec. blk 7..8198: claim one (colgroup, bn) via per-group
// atomic counters, preferring colgroup == own XCD id so each XCD's L2 only
// sees its 2 MB slice of C0h. Work-stealing keeps correctness under ANY
// block->XCD mapping (wrong XCC id only costs locality, never drops work).
__global__ __launch_bounds__(256) void k_rootsx(
    const int* __restrict__ kb_values, const int* __restrict__ kb_types,
    const ushort_t* __restrict__ C0h, const float* __restrict__ T_emb,
    int* __restrict__ cnt, const int* __restrict__ dec,
    const float* __restrict__ C0, const float* __restrict__ hidden,
    const float* __restrict__ W_ihT, const float* __restrict__ W_hhT,
    const float* __restrict__ TQK, const float* __restrict__ b_ih,
    const float* __restrict__ b_hh, float* __restrict__ roots,
    float* __restrict__ gi, float* __restrict__ gh, float* __restrict__ tvec) {
  __shared__ __align__(16) char smem_raw[18944];
  __shared__ int claim;
  int blk = blockIdx.x, tid = threadIdx.x;
  if (blk >= 7) {
    if (tid == 0) {
      // HW_REG_XCC_ID (id 20, offset 0, width 32): imm = (31<<11)|20
      int xcc = __builtin_amdgcn_s_getreg((31 << 11) | 20) & 7;
      int got = -1;
      for (int a = 0; a < 8; ++a) {
        int g = (xcc + a) & 7;
        int bn = atomicAdd(&cnt[g], 1);
        if (bn < 1024) { got = (g << 10) | bn; break; }
      }
      claim = got;
    }
    __syncthreads();
    int cl = claim;
    if (cl < 0) return;
    int g = cl >> 10, bn = cl & 1023;
    int* sv = (int*)smem_raw;                  // 1024 ints (4 KB)
    int* st = (int*)(smem_raw + 4096);         // 256 ints (1 KB)
    float* ts = (float*)(smem_raw + 5120);     // 64x36 fl (9216 B)
    float* psum = (float*)(smem_raw + 14336);  // 32x36 fl (4608 B)
    const int* vptr = kb_values + (size_t)bn * LN * LV;
    for (int i = tid; i < LN * LV; i += 256) sv[i] = vptr[i];
    st[tid] = kb_types[(size_t)bn * LN + tid];
    for (int idx = tid; idx < 64 * 32; idx += 256) {
      int t = idx >> 5, c = idx & 31;
      ts[t * 36 + c] = T_emb[t * D_ + g * 32 + c];
    }
    __syncthreads();
    int r = tid >> 3, cp = tid & 7;  // rowslot 0..31, col-pack (4 cols)
    const ushort_t* slice = C0h + (size_t)g * VOCAB_ * 32;
    float a0 = 0.f, a1 = 0.f, a2 = 0.f, a3 = 0.f;
#pragma unroll 4
    for (int i = 0; i < 32; ++i) {
      int vIdx = i * 32 + r;
      int v = sv[vIdx];
      int t = st[vIdx >> 2];
      uint2 u = *(const uint2*)(slice + (size_t)v * 32 + cp * 4);
      const float* tw = &ts[t * 36 + cp * 4];
      a0 += tw[0] * bflo(u.x);
      a1 += tw[1] * bfhi(u.x);
      a2 += tw[2] * bflo(u.y);
      a3 += tw[3] * bfhi(u.y);
    }
    psum[r * 36 + cp * 4 + 0] = a0;
    psum[r * 36 + cp * 4 + 1] = a1;
    psum[r * 36 + cp * 4 + 2] = a2;
    psum[r * 36 + cp * 4 + 3] = a3;
    __syncthreads();
    if (tid < 32) {
      float s = 0.f;
#pragma unroll
      for (int rr = 0; rr < 32; ++rr) s += psum[rr * 36 + tid];
      roots[(size_t)bn * D_ + g * 32 + tid] = s;
    }
  } else {
    int g = blk;  // 0..2: gi, 3..5: gh, 6: tvec
    float* xs = (float*)smem_raw;  // [16][256] = 16 KB
    float acc[B_];
    if (g < 3) {
#pragma unroll
      for (int b = 0; b < B_; ++b)
        xs[b * D_ + tid] = C0[(size_t)dec[b] * D_ + tid];
      __syncthreads();
      int i = g * 256 + tid;
      float bias = b_ih[i];
#pragma unroll
      for (int b = 0; b < B_; ++b) acc[b] = bias;
#pragma unroll 4
      for (int j = 0; j < D_; ++j) {
        float w = W_ihT[(size_t)j * 768 + i];
#pragma unroll
        for (int b = 0; b < B_; ++b) acc[b] += xs[b * D_ + j] * w;
      }
#pragma unroll
      for (int b = 0; b < B_; ++b) gi[(size_t)b * 768 + i] = acc[b];
    } else if (g < 6) {
#pragma unroll
      for (int b = 0; b < B_; ++b) xs[b * D_ + tid] = hidden[b * D_ + tid];
      __syncthreads();
      int i = (g - 3) * 256 + tid;
      float bias = b_hh[i];
#pragma unroll
      for (int b = 0; b < B_; ++b) acc[b] = bias;
#pragma unroll 4
      for (int j = 0; j < D_; ++j) {
        float w = W_hhT[(size_t)j * 768 + i];
#pragma unroll
        for (int b = 0; b < B_; ++b) acc[b] += xs[b * D_ + j] * w;
      }
#pragma unroll
      for (int b = 0; b < B_; ++b) gh[(size_t)b * 768 + i] = acc[b];
    } else {
#pragma unroll
      for (int b = 0; b < B_; ++b) xs[b * D_ + tid] = hidden[b * D_ + tid];
      __syncthreads();
#pragma unroll
      for (int b = 0; b < B_; ++b) acc[b] = 0.f;
#pragma unroll 4
      for (int j = 0; j < D_; ++j) {
        float w = TQK[(size_t)j * D_ + tid];
#pragma unroll
        for (int b = 0; b < B_; ++b) acc[b] += xs[b * D_ + j] * w;
      }
#pragma unroll
      for (int b = 0; b < B_; ++b) tvec[b * D_ + tid] = acc[b];
    }
  }
}

// ---------------- K_mid: scores (1024 blocks) + S transpose (1536 blocks) ---
__global__ __launch_bounds__(256) void k_mid(
    const float* __restrict__ roots, const float* __restrict__ tvec,
    const float* __restrict__ S, float* __restrict__ scores,
    float* __restrict__ ST) {
  int blk = blockIdx.x, tid = threadIdx.x;
  if (blk < 1024) {
    int b = blk >> 6;
    float rv = roots[(size_t)blk * D_ + tid];
    float sc = rv * tvec[b * D_ + tid];
    float sm = rv;
    __shared__ float red[8];
    int lane = tid & 63, wave = tid >> 6;
    for (int o = 32; o > 0; o >>= 1) {
      sc += __shfl_xor(sc, o);
      sm += __shfl_xor(sm, o);
    }
    if (lane == 0) { red[wave] = sc; red[4 + wave] = sm; }
    __syncthreads();
    if (tid == 0) {
      float SC = red[0] + red[1] + red[2] + red[3];
      float SM = red[4] + red[5] + red[6] + red[7];
      scores[blk] = (SM == 0.0f) ? SC - 1000000000.0f : SC;
    }
  } else {
    // ST[hb][d][m] = S[hb][m][d]
    int t = blk - 1024;
    int hb = t >> 5;
    int tile = t & 31;
    int tm = tile & 3, td = tile >> 2;
    int tx = tid & 31, ty = tid >> 5;
    __shared__ float sm2[32 * 33];
    const float* Sp = S + (size_t)hb * M_ * D_;
    float* STp = ST + (size_t)hb * D_ * M_;
#pragma unroll
    for (int k = 0; k < 4; ++k)
      sm2[(ty + 8 * k) * 33 + tx] =
          Sp[(size_t)(tm * 32 + ty + 8 * k) * D_ + td * 32 + tx];
    __syncthreads();
#pragma unroll
    for (int k = 0; k < 4; ++k)
      STp[(size_t)(td * 32 + ty + 8 * k) * M_ + tm * 32 + tx] =
          sm2[tx * 33 + ty + 8 * k];
  }
}

// ---------------- K_chain: softmax/rbar/feat/GRU/hops (grid=16) -------------
__global__ __launch_bounds__(256) void k_chain(
    const float* __restrict__ scores, const float* __restrict__ roots,
    const float* __restrict__ WvT, const float* __restrict__ gi,
    const float* __restrict__ gh, const float* __restrict__ hidden,
    const float* __restrict__ S, const float* __restrict__ ST,
    float* __restrict__ h_new_out, float* __restrict__ cat,
    float* __restrict__ p_ptr) {
  int b = blockIdx.x, tid = threadIdx.x;
  __shared__ float wsh[NT], rs[D_], us[D_], lo[M_], loB[M_], pr[M_];
  if (tid < NT) {
    float s = scores[b * NT + tid];
    float m = s;
    for (int o = 32; o > 0; o >>= 1) m = fmaxf(m, __shfl_xor(m, o));
    float e = expf(s - m);
    float sum = e;
    for (int o = 32; o > 0; o >>= 1) sum += __shfl_xor(sum, o);
    wsh[tid] = e / sum;
  }
  __syncthreads();
  float rb = 0.f;
#pragma unroll 16
  for (int n = 0; n < NT; ++n)
    rb += wsh[n] * roots[((size_t)(b * NT + n)) * D_ + tid];
  rs[tid] = rb;
  __syncthreads();
  float feat = 0.f;
#pragma unroll 16
  for (int j = 0; j < D_; ++j) feat += rs[j] * WvT[(size_t)j * D_ + tid];
  {
    float i_r = gi[(size_t)b * 768 + tid];
    float i_z = gi[(size_t)b * 768 + 256 + tid];
    float i_n = gi[(size_t)b * 768 + 512 + tid];
    float h_r = gh[(size_t)b * 768 + tid];
    float h_z = gh[(size_t)b * 768 + 256 + tid];
    float h_n = gh[(size_t)b * 768 + 512 + tid];
    float h = hidden[b * D_ + tid];
    float r = 1.f / (1.f + expf(-(i_r + h_r)));
    float z = 1.f / (1.f + expf(-(i_z + h_z)));
    float nn = tanhf(i_n + r * h_n);
    float hn = (1.f - z) * nn + z * h;
    h_new_out[b * D_ + tid] = hn;
    float u0 = hn + feat;
    us[tid] = u0;
    cat[b * 512 + tid] = u0;
  }
  __syncthreads();
  for (int h = 0; h < 3; ++h) {
    {
      int m = tid & 127;
      int half = tid >> 7;
      const float* STp = ST + (((size_t)h * B_ + b) * D_ + half * 128) * M_;
      float l = 0.f;
#pragma unroll 16
      for (int d = 0; d < 128; ++d)
        l += us[half * 128 + d] * STp[(size_t)d * M_ + m];
      if (half == 0) lo[m] = l; else loB[m] = l;
    }
    __syncthreads();
    if (h == 2) {
      if (tid < M_) p_ptr[b * M_ + tid] = lo[tid] + loB[tid];
      break;
    }
    if (tid < 64) {
      float l0 = lo[tid] + loB[tid], l1 = lo[tid + 64] + loB[tid + 64];
      float a = fmaxf(l0, l1);
      for (int o = 32; o > 0; o >>= 1) a = fmaxf(a, __shfl_xor(a, o));
      float e0 = expf(l0 - a), e1 = expf(l1 - a);
      float s = e0 + e1;
      for (int o = 32; o > 0; o >>= 1) s += __shfl_xor(s, o);
      pr[tid] = e0 / s;
      pr[tid + 64] = e1 / s;
    }
    __syncthreads();
    {
      const float* Sn = S + (((size_t)(h + 1) * B_ + b) * M_) * D_;
      float o = 0.f;
#pragma unroll 16
      for (int m = 0; m < M_; ++m) o += pr[m] * Sn[(size_t)m * D_ + tid];
      if (h == 0) cat[b * 512 + D_ + tid] = o;
      us[tid] += o;
    }
    __syncthreads();
  }
}

// ---------------- K_pvocab: p_vocab = cat @ W1_w^T + b ----------------------
__global__ __launch_bounds__(256) void k_pvocab(
    const float* __restrict__ cat, const float* __restrict__ W1_w,
    const float* __restrict__ W1_b, float* __restrict__ out) {
  int blk = blockIdx.x, tid = threadIdx.x;
  int row = tid & 63, q = tid >> 6;  // q in 0..3 (k quarter)
  int v = blk * 64 + row;
  __shared__ float cs[B_ * 512];
  __shared__ float ps[3][64][B_];
  for (int i = tid; i < B_ * 512; i += 256) cs[i] = cat[i];
  __syncthreads();
  const float4* wrow = (const float4*)(W1_w + (size_t)v * 512 + q * 128);
  float acc[B_];
#pragma unroll
  for (int b = 0; b < B_; ++b) acc[b] = 0.f;
#pragma unroll 4
  for (int k4 = 0; k4 < 32; ++k4) {
    float4 w = wrow[k4];
#pragma unroll
    for (int b = 0; b < B_; ++b) {
      const float* c = &cs[b * 512 + q * 128 + k4 * 4];
      acc[b] += w.x * c[0] + w.y * c[1] + w.z * c[2] + w.w * c[3];
    }
  }
  if (q > 0) {
#pragma unroll
    for (int b = 0; b < B_; ++b) ps[q - 1][row][b] = acc[b];
  }
  __syncthreads();
  if (q == 0) {
    float bb = W1_b[v];
#pragma unroll
    for (int b = 0; b < B_; ++b)
      out[(size_t)b * VOCAB_ + v] =
          acc[b] + ps[0][row][b] + ps[1][row][b] + ps[2][row][b] + bb;
  }
}

extern "C" void kernel_launch(void* const* d_in, const int* in_sizes, int n_in,
                              void* d_out, int out_size, void* d_ws,
                              size_t ws_size, hipStream_t stream) {
  const int* decoder_input = (const int*)d_in[0];
  const int* story = (const int*)d_in[1];
  const float* hidden = (const float*)d_in[2];
  const int* kb_values = (const int*)d_in[3];
  const int* kb_types = (const int*)d_in[4];
  const float* C = (const float*)d_in[7];
  const float* T_emb = (const float*)d_in[8];
  const float* Wq = (const float*)d_in[9];
  const float* Wk = (const float*)d_in[10];
  const float* Wv = (const float*)d_in[11];
  const float* W1_w = (const float*)d_in[12];
  const float* W1_b = (const float*)d_in[13];
  const float* W_ih = (const float*)d_in[14];
  const float* W_hh = (const float*)d_in[15];
  const float* b_ih = (const float*)d_in[16];
  const float* b_hh = (const float*)d_in[17];

  float* out = (float*)d_out;
  float* p_ptr = out;                          // (16,128)
  float* p_vocab = out + B_ * M_;              // (16,32000)
  float* h_new = out + B_ * M_ + B_ * VOCAB_;  // (16,256)

  // workspace layout (floats). ST aliases W_ihT/W_hhT/TQK (dead by then).
  float* ws = (float*)d_ws;
  float* S = ws;                          // 1,572,864
  float* roots = S + 3 * B_ * M_ * D_;    //   262,144
  float* cat = roots + B_ * NT * D_;      //     8,192
  float* scores = cat + B_ * 512;         //     1,024
  float* gi = scores + B_ * NT;           //    12,288
  float* gh = gi + B_ * 768;              //    12,288
  float* tvec = gh + B_ * 768;            //     4,096
  int* cnt = (int*)(tvec + B_ * D_);      //        16 ints
  ushort_t* C0h = (ushort_t*)(cnt + 16);  // 8,192,000 ushorts (16 MB)
  float* wtmp = (float*)(C0h + (size_t)VOCAB_ * D_);
  float* W_ihT = wtmp;                    //   196,608
  float* W_hhT = W_ihT + 768 * D_;        //   196,608
  float* TQK = W_hhT + 768 * D_;          //    65,536
  float* ST = wtmp;                       // alias: 1,572,864
  float* WvT = wtmp + 3 * B_ * M_ * D_;   //    65,536 (after ST region)

  hipMemsetAsync(cnt, 0, 16 * sizeof(int), stream);
  hipLaunchKernelGGL(k_prep,
                     dim3(NB_S + NB_CONV + 2 * NB_TR + NB_TQK + NB_WVT),
                     dim3(256), 0, stream, story, C, W_ih, W_hh, Wq, Wk, Wv, S,
                     C0h, W_ihT, W_hhT, TQK, WvT);
  hipLaunchKernelGGL(k_rootsx, dim3(7 + 8 * 1024), dim3(256), 0, stream,
                     kb_values, kb_types, C0h, T_emb, cnt, decoder_input, C,
                     hidden, W_ihT, W_hhT, TQK, b_ih, b_hh, roots, gi, gh,
                     tvec);
  hipLaunchKernelGGL(k_mid, dim3(1024 + 1536), dim3(256), 0, stream, roots,
                     tvec, S, scores, ST);
  hipLaunchKernelGGL(k_chain, dim3(B_), dim3(256), 0, stream, scores, roots,
                     WvT, gi, gh, hidden, S, ST, h_new, cat, p_ptr);
  hipLaunchKernelGGL(k_pvocab, dim3(VOCAB_ / 64), dim3(256), 0, stream, cat,
                     W1_w, W1_b, p_vocab);
}